// Round 24
// baseline (138.068 us; speedup 1.0000x reference)
//
#include <hip/hip_runtime.h>
#include <math.h>

#define D_DIM   256
#define N_ROWS  16384
#define K_CODES 8192
#define NCHUNK  8          // 8 chunks of 1024 codes

typedef __attribute__((ext_vector_type(8))) _Float16 h8v;        // 8 f16 (A/B frag)
typedef __attribute__((ext_vector_type(4))) float f4v;           // 4 f32  (C/D frag)
typedef __attribute__((ext_vector_type(4))) unsigned short us4;  // 4 f16 (8B write)
typedef unsigned long long u64;
typedef unsigned int u32;

// out layout: [0, 4194304) z_q_st | [4194304, 4210688) indices (as float) | [4210688] vq_loss
#define IDX_OFF  ((size_t)N_ROWS * D_DIM)
#define LOSS_OFF (IDX_OFF + N_ROWS)

// ws layout (15 MB used):
//   [0, 2MB)        u64 cand[N_ROWS][NCHUNK][2]
//   [2MB, +32KB)    float enorm[8192]
//   [+32KB, +16KB)  float partials[4096]
//   [3MB, 11MB)     f16 zh_t  K-major: [d0b][lg][row][16B]  (d0b<8, lg<4)
//   [11MB, 15MB)    f16 eh_t  [d0b][lg][code][16B]
#define WS_ENORM_OFF    (2u * 1024u * 1024u)
#define WS_PARTIAL_OFF  (WS_ENORM_OFF + 32768u)
#define WS_ZH_OFF       (3u * 1024u * 1024u)
#define WS_EH_OFF       (11u * 1024u * 1024u)

__device__ __forceinline__ unsigned short f2h(float f) {    // fp32 -> fp16 RNE
    _Float16 h = (_Float16)f;
    unsigned short u;
    __builtin_memcpy(&u, &h, 2);
    return u;
}
__device__ __forceinline__ u32 f2ord(float f) {             // monotonic fp32 -> u32
    u32 u = __float_as_uint(f);
    return (u & 0x80000000u) ? ~u : (u | 0x80000000u);
}
__device__ __forceinline__ void gl2lds16(const void* g, void* l) {
    __builtin_amdgcn_global_load_lds(
        (const __attribute__((address_space(1))) unsigned int*)g,
        (__attribute__((address_space(3))) unsigned int*)l, 16, 0, 0);
}

// ---- pre-convert: z -> zh_t fp16 (K-major tiling) ----
__global__ __launch_bounds__(256) void zconv_kernel(const float* __restrict__ z,
                                                    unsigned short* __restrict__ zh) {
    int q = blockIdx.x * 256 + threadIdx.x;        // float4 index, 0..1048575
    float4 v = reinterpret_cast<const float4*>(z)[q];
    us4 h;
    h[0] = f2h(v.x); h[1] = f2h(v.y); h[2] = f2h(v.z); h[3] = f2h(v.w);
    int row = q >> 6;                               // 64 float4 per row
    int f   = q & 63;                               // d = f*4 .. f*4+3
    int d0b = f >> 3, lg = (f >> 1) & 3, half = f & 1;
    size_t off = ((size_t)(d0b * 4 + lg) * N_ROWS + row) * 16 + half * 8;
    *reinterpret_cast<us4*>((char*)zh + off) = h;
}

// ---- pre-convert: emb -> eh_t fp16 (K-major tiling) + enorm (fused) ----
__global__ __launch_bounds__(256) void econv_kernel(const float* __restrict__ emb,
                                                    unsigned short* __restrict__ eh,
                                                    float* __restrict__ enorm) {
    int q = blockIdx.x * 256 + threadIdx.x;        // 0..524287
    float4 v = reinterpret_cast<const float4*>(emb)[q];

    // one wave == one codebook row (64 lanes x 4 floats): fused enorm
    float s = v.x * v.x + v.y * v.y + v.z * v.z + v.w * v.w;
    #pragma unroll
    for (int off = 32; off >= 1; off >>= 1) s += __shfl_down(s, off);

    us4 h;
    h[0] = f2h(v.x); h[1] = f2h(v.y); h[2] = f2h(v.z); h[3] = f2h(v.w);
    int row = q >> 6;
    int f   = q & 63;
    if (f == 0) enorm[row] = s;
    int d0b = f >> 3, lg = (f >> 1) & 3, half = f & 1;
    size_t off = ((size_t)(d0b * 4 + lg) * K_CODES + row) * 16 + half * 8;
    *reinterpret_cast<us4*>((char*)eh + off) = h;
}

// ---------------- MFMA argmin: fp16 screen, z register-resident ----------------
// ROUND-24 CHANGE (vs round-23): tournament epilogue -> sequential top-2
// update (round-12 style, ~10 live temps vs ~48). Round-23 spilled 22.5MB
// (live ~278 > 256): the tournament's en[16]+v/g[32] temps were the excess.
// New live ~248 < 256 -> no spill expected.
// Tripwire: WRITE_SIZE >= 1MB -> still spilling -> round-23 kernel is final.
// Keeps: fp16 1-pass screen, zAll[8][4] register-resident (128 VGPR, static
// indexing via runtime-ct x unrolled-q), XCD 16x8 rectangle, e-only LDS dbuf,
// LDS enorm, single barrier per step, (256,2).
__global__ __launch_bounds__(256, 2) void argmin_kernel(const unsigned short* __restrict__ zh,
                                                        const unsigned short* __restrict__ eh,
                                                        const float* __restrict__ enorm,
                                                        u64* __restrict__ cand) {
    __shared__ __align__(16) unsigned char lds[36864];   // 2x16KB e-dbuf + 4KB enorm

    const int tid = threadIdx.x;
    const int wv  = tid >> 6;
    const int l   = tid & 63;
    const int lr  = l & 15;
    const int lg  = l >> 4;
    const int wm  = wv >> 1;                // row half: rows wm*64..+63
    const int wn  = wv & 1;                 // code half: codes wn*64..+63
    const int wg  = blockIdx.x;
    const int x   = wg & 7;                 // XCD (round-robin dispatch)
    const int i   = wg >> 3;                // 0..127 within XCD
    const int ch  = i >> 4;                 // chunk 0..7
    const int r0    = x * 2048 + (i & 15) * 128;   // row-block in XCD's 2048-row slice
    const int cbase = ch * 1024;

    const char* zhp = (const char*)zh;
    const char* ehp = (const char*)eh;

    // enorm slice -> LDS via normal load + ds_write (no vmcnt-queue pollution)
    {
        float4 ev = *reinterpret_cast<const float4*>(enorm + cbase + tid * 4);
        *reinterpret_cast<float4*>(lds + 32768 + tid * 16) = ev;
    }

    // e-stage per-thread source bases; per-step offsets: d0b<<19, ct<<11
    const int tsw = tid >> 7, tix = tid & 127;
    const size_t E0a = ((size_t)tsw       * K_CODES + cbase + tix) * 16;
    const size_t E0b = ((size_t)(tsw + 2) * K_CODES + cbase + tix) * 16;

    // stage step (ctn, qq) into buffer b; qq static, ctn runtime
    auto stage2 = [&](int ctn, int qq, int b) {
        char* dst = (char*)lds + b * 16384 + tid * 16;
        const size_t u0 = (((size_t)(qq * 2)) << 19) + (((size_t)ctn) << 11);
        const size_t u1 = u0 + (1u << 19);
        gl2lds16(ehp + E0a + u0, dst);
        gl2lds16(ehp + E0b + u0, dst + 4096);
        gl2lds16(ehp + E0a + u1, dst + 8192);
        gl2lds16(ehp + E0b + u1, dst + 12288);
    };

    // ---- ALL z fragments into registers once (128 VGPR, static-indexed) ----
    h8v zAll[8][4];
    {
        size_t Zb[4];
        #pragma unroll
        for (int j = 0; j < 4; ++j)
            Zb[j] = ((size_t)lg * N_ROWS + r0 + wm * 64 + j * 16 + lr) * 16;
        #pragma unroll
        for (int d = 0; d < 8; ++d)
            #pragma unroll
            for (int j = 0; j < 4; ++j)
                zAll[d][j] = *reinterpret_cast<const h8v*>(
                    zhp + Zb[j] + ((size_t)d << 20));
    }

    u64 t1[4], t2[4];                       // top-2 per owned row-tile j
    #pragma unroll
    for (int j = 0; j < 4; ++j) { t1[j] = ~0ULL; t2[j] = ~0ULL; }

    f4v acc[4][4];
    #pragma unroll
    for (int i2 = 0; i2 < 4; ++i2)
        #pragma unroll
        for (int j = 0; j < 4; ++j)
            acc[i2][j] = (f4v){0.f, 0.f, 0.f, 0.f};

    stage2(0, 0, 0);
    __syncthreads();                        // buf0 + enorm ready

    for (int ct = 0; ct < 8; ++ct) {
        #pragma unroll
        for (int q = 0; q < 4; ++q) {       // fully unrolled: all indices static
            const int b = q & 1;
            // prefetch next step into the other buffer
            if (q < 3)           stage2(ct, q + 1, b ^ 1);
            else if (ct < 7)     stage2(ct + 1, 0, 0);

            {
                const char* base = (const char*)lds + b * 16384;
                #pragma unroll
                for (int h = 0; h < 2; ++h)
                    #pragma unroll
                    for (int i2 = 0; i2 < 4; ++i2) {
                        int code = wn * 64 + i2 * 16 + lr;
                        h8v ehf = *reinterpret_cast<const h8v*>(
                            base + h * 8192 + lg * 2048 + code * 16);
                        #pragma unroll
                        for (int j = 0; j < 4; ++j)
                            acc[i2][j] = __builtin_amdgcn_mfma_f32_16x16x32_f16(
                                ehf, zAll[2 * q + h][j], acc[i2][j], 0, 0, 0);
                    }
            }

            if (q == 3) {
                // epilogue for this ct: dist = enorm - 2*dot (enorm from LDS);
                // SEQUENTIAL top-2 update (low register footprint, no spill).
                const int cbl = ct * 128;
                const int cb  = cbase + cbl;
                #pragma unroll
                for (int i2 = 0; i2 < 4; ++i2)
                    #pragma unroll
                    for (int r = 0; r < 4; ++r) {
                        int cloc = cbl + wn * 64 + i2 * 16 + lg * 4 + r;
                        float en = *reinterpret_cast<const float*>(
                            lds + 32768 + cloc * 4);
                        u32 code = (u32)(cb + wn * 64 + i2 * 16 + lg * 4 + r);
                        #pragma unroll
                        for (int j = 0; j < 4; ++j) {
                            float dist = fmaf(-2.f, acc[i2][j][r], en);
                            u64 key = ((u64)f2ord(dist) << 32) | code;
                            if (key < t1[j])      { t2[j] = t1[j]; t1[j] = key; }
                            else if (key < t2[j]) { t2[j] = key; }
                        }
                    }
                #pragma unroll
                for (int i2 = 0; i2 < 4; ++i2)
                    #pragma unroll
                    for (int j = 0; j < 4; ++j)
                        acc[i2][j] = (f4v){0.f, 0.f, 0.f, 0.f};
            }

            __syncthreads();                // drains prefetch; buf swap safe
        }
    }

    // cross-lane (lg) top-2 merge: lanes sharing (j, lr) hold same z-row
    #pragma unroll
    for (int j = 0; j < 4; ++j) {
        u64 a1 = t1[j], a2 = t2[j];
        #pragma unroll
        for (int mk = 16; mk <= 32; mk <<= 1) {
            u64 o1 = __shfl_xor(a1, mk);
            u64 o2 = __shfl_xor(a2, mk);
            u64 n1 = a1 < o1 ? a1 : o1;
            u64 hi = a1 < o1 ? o1 : a1;
            u64 m2 = a2 < o2 ? a2 : o2;
            a1 = n1;
            a2 = hi < m2 ? hi : m2;
        }
        t1[j] = a1; t2[j] = a2;
    }

    // cross-wave (wn) merge via LDS, then write cand[row][ch][2]
    __syncthreads();
    u64* mbuf = (u64*)lds;                   // 2KB reuse
    if (wn == 1 && lg == 0) {
        #pragma unroll
        for (int j = 0; j < 4; ++j) {
            int s = ((wm * 4 + j) * 16 + lr) * 2;
            mbuf[s] = t1[j]; mbuf[s + 1] = t2[j];
        }
    }
    __syncthreads();
    if (wn == 0 && lg == 0) {
        #pragma unroll
        for (int j = 0; j < 4; ++j) {
            int s = ((wm * 4 + j) * 16 + lr) * 2;
            u64 b1 = mbuf[s], b2 = mbuf[s + 1];
            u64 n1 = t1[j] < b1 ? t1[j] : b1;
            u64 hi = t1[j] < b1 ? b1 : t1[j];
            u64 m2 = t2[j] < b2 ? t2[j] : b2;
            u64 n2 = hi < m2 ? hi : m2;
            int row = r0 + wm * 64 + j * 16 + lr;
            cand[((size_t)row * NCHUNK + ch) * 2]     = n1;
            cand[((size_t)row * NCHUNK + ch) * 2 + 1] = n2;
        }
    }
}

// ---------------- exact fp32 rescore of 16 candidates + outputs ----------------
__global__ __launch_bounds__(256) void rescore_kernel(const float* __restrict__ z,
                                                      const float* __restrict__ emb,
                                                      const float* __restrict__ enorm,
                                                      const u64* __restrict__ cand,
                                                      float* __restrict__ out,
                                                      float* __restrict__ partials) {
    int row  = blockIdx.x * 4 + (threadIdx.x >> 6);
    int lane = threadIdx.x & 63;
    float4 zv = reinterpret_cast<const float4*>(z)[(size_t)row * 64 + lane];

    u64 best = ~0ULL;
    for (int s = 0; s < 2 * NCHUNK; ++s) {
        u32 c = ((u32)cand[(size_t)row * (2 * NCHUNK) + s]) & (K_CODES - 1);
        float4 ev = reinterpret_cast<const float4*>(emb)[(size_t)c * 64 + lane];
        float p = zv.x * ev.x + zv.y * ev.y + zv.z * ev.z + zv.w * ev.w;
        #pragma unroll
        for (int mk = 1; mk < 64; mk <<= 1) p += __shfl_xor(p, mk);
        float dist = fmaf(-2.f, p, enorm[c]);
        u64 key = ((u64)f2ord(dist) << 32) | c;
        best = key < best ? key : best;
    }
    u32 idx = ((u32)best) & (K_CODES - 1);
    if (lane == 0) out[IDX_OFF + row] = (float)idx;

    float4 ev = reinterpret_cast<const float4*>(emb)[(size_t)idx * 64 + lane];
    float tx = ev.x - zv.x, ty = ev.y - zv.y, tz = ev.z - zv.z, tw = ev.w - zv.w;
    float4 o;
    o.x = zv.x + tx; o.y = zv.y + ty; o.z = zv.z + tz; o.w = zv.w + tw;  // straight-through
    reinterpret_cast<float4*>(out)[(size_t)row * 64 + lane] = o;

    float s = tx * tx + ty * ty + tz * tz + tw * tw;
    #pragma unroll
    for (int off = 32; off >= 1; off >>= 1) s += __shfl_down(s, off);

    __shared__ float wsum[4];
    if (lane == 0) wsum[threadIdx.x >> 6] = s;
    __syncthreads();
    if (threadIdx.x == 0)
        partials[blockIdx.x] = (wsum[0] + wsum[1]) + (wsum[2] + wsum[3]);
}

__global__ __launch_bounds__(256) void loss_kernel(const float* __restrict__ partials,
                                                   float* __restrict__ out) {
    __shared__ float sm[256];
    float s = 0.0f;
    for (int i = threadIdx.x; i < 4096; i += 256) s += partials[i];
    sm[threadIdx.x] = s;
    __syncthreads();
    #pragma unroll
    for (int st = 128; st >= 1; st >>= 1) {
        if (threadIdx.x < st) sm[threadIdx.x] += sm[threadIdx.x + st];
        __syncthreads();
    }
    if (threadIdx.x == 0)
        out[LOSS_OFF] = sm[0] * (0.25f / (float)(N_ROWS * D_DIM));
}

extern "C" void kernel_launch(void* const* d_in, const int* in_sizes, int n_in,
                              void* d_out, int out_size, void* d_ws, size_t ws_size,
                              hipStream_t stream) {
    const float* z   = (const float*)d_in[0];
    const float* emb = (const float*)d_in[1];
    float* out = (float*)d_out;

    u64*   cand     = (u64*)d_ws;
    float* enorm    = (float*)((char*)d_ws + WS_ENORM_OFF);
    float* partials = (float*)((char*)d_ws + WS_PARTIAL_OFF);
    unsigned short* zh = (unsigned short*)((char*)d_ws + WS_ZH_OFF);
    unsigned short* eh = (unsigned short*)((char*)d_ws + WS_EH_OFF);

    zconv_kernel<<<4096, 256, 0, stream>>>(z, zh);
    econv_kernel<<<2048, 256, 0, stream>>>(emb, eh, enorm);
    argmin_kernel<<<1024, 256, 0, stream>>>(zh, eh, enorm, cand);
    rescore_kernel<<<N_ROWS / 4, 256, 0, stream>>>(z, emb, enorm, cand, out, partials);
    loss_kernel<<<1, 256, 0, stream>>>(partials, out);
}

// Round 25
// 135.527 us; speedup vs baseline: 1.0187x; 1.0187x over previous
//
#include <hip/hip_runtime.h>
#include <math.h>

#define D_DIM   256
#define N_ROWS  16384
#define K_CODES 8192
#define NCHUNK  8          // 8 chunks of 1024 codes

typedef __attribute__((ext_vector_type(8))) _Float16 h8v;        // 8 f16 (A/B frag)
typedef __attribute__((ext_vector_type(4))) float f4v;           // 4 f32  (C/D frag)
typedef __attribute__((ext_vector_type(4))) unsigned short us4;  // 4 f16 (8B write)
typedef unsigned long long u64;
typedef unsigned int u32;

// out layout: [0, 4194304) z_q_st | [4194304, 4210688) indices (as float) | [4210688] vq_loss
#define IDX_OFF  ((size_t)N_ROWS * D_DIM)
#define LOSS_OFF (IDX_OFF + N_ROWS)

// ws layout (15 MB used):
//   [0, 2MB)        u64 cand[N_ROWS][NCHUNK][2]
//   [2MB, +32KB)    float enorm[8192]
//   [+32KB, +16KB)  float partials[4096]
//   [3MB, 11MB)     f16 zh_t  K-major: [d0b][lg][row][16B]  (d0b<8, lg<4)
//   [11MB, 15MB)    f16 eh_t  [d0b][lg][code][16B]
#define WS_ENORM_OFF    (2u * 1024u * 1024u)
#define WS_PARTIAL_OFF  (WS_ENORM_OFF + 32768u)
#define WS_ZH_OFF       (3u * 1024u * 1024u)
#define WS_EH_OFF       (11u * 1024u * 1024u)

__device__ __forceinline__ unsigned short f2h(float f) {    // fp32 -> fp16 RNE
    _Float16 h = (_Float16)f;
    unsigned short u;
    __builtin_memcpy(&u, &h, 2);
    return u;
}
__device__ __forceinline__ u32 f2ord(float f) {             // monotonic fp32 -> u32
    u32 u = __float_as_uint(f);
    return (u & 0x80000000u) ? ~u : (u | 0x80000000u);
}
__device__ __forceinline__ void gl2lds16(const void* g, void* l) {
    __builtin_amdgcn_global_load_lds(
        (const __attribute__((address_space(1))) unsigned int*)g,
        (__attribute__((address_space(3))) unsigned int*)l, 16, 0, 0);
}

// ---- pre-convert: z -> zh_t fp16 (K-major tiling) ----
__global__ __launch_bounds__(256) void zconv_kernel(const float* __restrict__ z,
                                                    unsigned short* __restrict__ zh) {
    int q = blockIdx.x * 256 + threadIdx.x;        // float4 index, 0..1048575
    float4 v = reinterpret_cast<const float4*>(z)[q];
    us4 h;
    h[0] = f2h(v.x); h[1] = f2h(v.y); h[2] = f2h(v.z); h[3] = f2h(v.w);
    int row = q >> 6;                               // 64 float4 per row
    int f   = q & 63;                               // d = f*4 .. f*4+3
    int d0b = f >> 3, lg = (f >> 1) & 3, half = f & 1;
    size_t off = ((size_t)(d0b * 4 + lg) * N_ROWS + row) * 16 + half * 8;
    *reinterpret_cast<us4*>((char*)zh + off) = h;
}

// ---- pre-convert: emb -> eh_t fp16 (K-major tiling) + enorm (fused) ----
__global__ __launch_bounds__(256) void econv_kernel(const float* __restrict__ emb,
                                                    unsigned short* __restrict__ eh,
                                                    float* __restrict__ enorm) {
    int q = blockIdx.x * 256 + threadIdx.x;        // 0..524287
    float4 v = reinterpret_cast<const float4*>(emb)[q];

    // one wave == one codebook row (64 lanes x 4 floats): fused enorm
    float s = v.x * v.x + v.y * v.y + v.z * v.z + v.w * v.w;
    #pragma unroll
    for (int off = 32; off >= 1; off >>= 1) s += __shfl_down(s, off);

    us4 h;
    h[0] = f2h(v.x); h[1] = f2h(v.y); h[2] = f2h(v.z); h[3] = f2h(v.w);
    int row = q >> 6;
    int f   = q & 63;
    if (f == 0) enorm[row] = s;
    int d0b = f >> 3, lg = (f >> 1) & 3, half = f & 1;
    size_t off = ((size_t)(d0b * 4 + lg) * K_CODES + row) * 16 + half * 8;
    *reinterpret_cast<us4*>((char*)eh + off) = h;
}

// ---------------- MFMA argmin: fp16 screen, z fully register-resident ----------------
// FINAL (round-23 verified best: total 135.7us, argmin 103us, absmax 0).
// Ladder: 885 (fp32 VALU) -> 428 (bf16 split MFMA + top2 + exact rescore)
// -> 290 (T3 single-barrier pipeline) -> 245 (z in regs) -> 233 (XCD 16x8
// rectangle: FETCH 523->41MB) -> 145 (fp16 1-pass screen) -> 135.7 (zAll
// register-resident). Correctness: per-lane top-2 per (row,chunk) + exact
// fp32 rescore of 16 cand/row absorbs fp16 screen error (crowding P~1e-9/row).
// Accepted: one-shot ~22MB prologue spill (empirically cheaper than low-reg
// epilogue variants, rounds 21/24).
__global__ __launch_bounds__(256, 2) void argmin_kernel(const unsigned short* __restrict__ zh,
                                                        const unsigned short* __restrict__ eh,
                                                        const float* __restrict__ enorm,
                                                        u64* __restrict__ cand) {
    __shared__ __align__(16) unsigned char lds[36864];   // 2x16KB e-dbuf + 4KB enorm

    const int tid = threadIdx.x;
    const int wv  = tid >> 6;
    const int l   = tid & 63;
    const int lr  = l & 15;
    const int lg  = l >> 4;
    const int wm  = wv >> 1;                // row half: rows wm*64..+63
    const int wn  = wv & 1;                 // code half: codes wn*64..+63
    const int wg  = blockIdx.x;
    const int x   = wg & 7;                 // XCD (round-robin dispatch)
    const int i   = wg >> 3;                // 0..127 within XCD
    const int ch  = i >> 4;                 // chunk 0..7
    const int r0    = x * 2048 + (i & 15) * 128;   // row-block in XCD's 2048-row slice
    const int cbase = ch * 1024;

    const char* zhp = (const char*)zh;
    const char* ehp = (const char*)eh;

    // enorm slice -> LDS via normal load + ds_write (no vmcnt-queue pollution)
    {
        float4 ev = *reinterpret_cast<const float4*>(enorm + cbase + tid * 4);
        *reinterpret_cast<float4*>(lds + 32768 + tid * 16) = ev;
    }

    // e-stage per-thread source bases; per-step offsets: d0b<<19, ct<<11
    const int tsw = tid >> 7, tix = tid & 127;
    const size_t E0a = ((size_t)tsw       * K_CODES + cbase + tix) * 16;
    const size_t E0b = ((size_t)(tsw + 2) * K_CODES + cbase + tix) * 16;

    // stage step (ctn, qq) into buffer b; qq static, ctn runtime
    auto stage2 = [&](int ctn, int qq, int b) {
        char* dst = (char*)lds + b * 16384 + tid * 16;
        const size_t u0 = (((size_t)(qq * 2)) << 19) + (((size_t)ctn) << 11);
        const size_t u1 = u0 + (1u << 19);
        gl2lds16(ehp + E0a + u0, dst);
        gl2lds16(ehp + E0b + u0, dst + 4096);
        gl2lds16(ehp + E0a + u1, dst + 8192);
        gl2lds16(ehp + E0b + u1, dst + 12288);
    };

    // ---- ALL z fragments into registers once (128 VGPR, static-indexed) ----
    h8v zAll[8][4];
    {
        size_t Zb[4];
        #pragma unroll
        for (int j = 0; j < 4; ++j)
            Zb[j] = ((size_t)lg * N_ROWS + r0 + wm * 64 + j * 16 + lr) * 16;
        #pragma unroll
        for (int d = 0; d < 8; ++d)
            #pragma unroll
            for (int j = 0; j < 4; ++j)
                zAll[d][j] = *reinterpret_cast<const h8v*>(
                    zhp + Zb[j] + ((size_t)d << 20));
    }

    u64 t1[4], t2[4];                       // top-2 per owned row-tile j
    #pragma unroll
    for (int j = 0; j < 4; ++j) { t1[j] = ~0ULL; t2[j] = ~0ULL; }

    f4v acc[4][4];
    #pragma unroll
    for (int i2 = 0; i2 < 4; ++i2)
        #pragma unroll
        for (int j = 0; j < 4; ++j)
            acc[i2][j] = (f4v){0.f, 0.f, 0.f, 0.f};

    stage2(0, 0, 0);
    __syncthreads();                        // buf0 + enorm ready

    for (int ct = 0; ct < 8; ++ct) {
        #pragma unroll
        for (int q = 0; q < 4; ++q) {       // fully unrolled: all indices static
            const int b = q & 1;
            // prefetch next step into the other buffer
            if (q < 3)           stage2(ct, q + 1, b ^ 1);
            else if (ct < 7)     stage2(ct + 1, 0, 0);

            {
                const char* base = (const char*)lds + b * 16384;
                #pragma unroll
                for (int h = 0; h < 2; ++h)
                    #pragma unroll
                    for (int i2 = 0; i2 < 4; ++i2) {
                        int code = wn * 64 + i2 * 16 + lr;
                        h8v ehf = *reinterpret_cast<const h8v*>(
                            base + h * 8192 + lg * 2048 + code * 16);
                        #pragma unroll
                        for (int j = 0; j < 4; ++j)
                            acc[i2][j] = __builtin_amdgcn_mfma_f32_16x16x32_f16(
                                ehf, zAll[2 * q + h][j], acc[i2][j], 0, 0, 0);
                    }
            }

            if (q == 3) {
                // epilogue for this ct: dist = enorm - 2*dot (enorm from LDS),
                // fp32 (value,slot) tournament top-2 per row j, u64 key merge.
                const int cbl = ct * 128;
                const int cb  = cbase + cbl;
                float en[16];
                #pragma unroll
                for (int i2 = 0; i2 < 4; ++i2)
                    #pragma unroll
                    for (int r = 0; r < 4; ++r)
                        en[i2 * 4 + r] = *reinterpret_cast<const float*>(
                            lds + 32768 + (cbl + wn * 64 + i2 * 16 + lg * 4 + r) * 4);
                #pragma unroll
                for (int j = 0; j < 4; ++j) {
                    float v1[8], v2[8]; int g1[8], g2[8];
                    #pragma unroll
                    for (int k = 0; k < 8; ++k) {
                        int a = 2 * k, c = 2 * k + 1;
                        float da = fmaf(-2.f, acc[a >> 2][j][a & 3], en[a]);
                        float dc = fmaf(-2.f, acc[c >> 2][j][c & 3], en[c]);
                        bool w = dc < da;             // strict: tie -> smaller slot
                        v1[k] = w ? dc : da; g1[k] = w ? c : a;
                        v2[k] = w ? da : dc; g2[k] = w ? a : c;
                    }
                    #pragma unroll
                    for (int st = 4; st >= 1; st >>= 1)
                        #pragma unroll
                        for (int m = 0; m < st; ++m) {
                            float b1 = v1[m + st], b2 = v2[m + st];
                            int  b1s = g1[m + st], b2s = g2[m + st];
                            bool c1 = b1 < v1[m];
                            float hv = c1 ? v1[m] : b1;  int hs = c1 ? g1[m] : b1s;
                            v1[m] = c1 ? b1 : v1[m];     g1[m] = c1 ? b1s : g1[m];
                            bool c2 = b2 < v2[m];
                            float mv = c2 ? b2 : v2[m];  int ms = c2 ? b2s : g2[m];
                            bool c3 = mv < hv;
                            v2[m] = c3 ? mv : hv;        g2[m] = c3 ? ms : hs;
                        }
                    int s1 = g1[0], s2 = g2[0];
                    u32 code1 = (u32)(cb + wn * 64 + ((s1 >> 2) << 4) + lg * 4 + (s1 & 3));
                    u32 code2 = (u32)(cb + wn * 64 + ((s2 >> 2) << 4) + lg * 4 + (s2 & 3));
                    u64 k1 = ((u64)f2ord(v1[0]) << 32) | code1;
                    u64 k2 = ((u64)f2ord(v2[0]) << 32) | code2;
                    u64 n1 = k1 < t1[j] ? k1 : t1[j];
                    u64 hi = k1 < t1[j] ? t1[j] : k1;
                    u64 m2 = k2 < t2[j] ? k2 : t2[j];
                    t1[j] = n1;
                    t2[j] = hi < m2 ? hi : m2;
                }
                #pragma unroll
                for (int i2 = 0; i2 < 4; ++i2)
                    #pragma unroll
                    for (int j = 0; j < 4; ++j)
                        acc[i2][j] = (f4v){0.f, 0.f, 0.f, 0.f};
            }

            __syncthreads();                // drains prefetch; buf swap safe
        }
    }

    // cross-lane (lg) top-2 merge: lanes sharing (j, lr) hold same z-row
    #pragma unroll
    for (int j = 0; j < 4; ++j) {
        u64 a1 = t1[j], a2 = t2[j];
        #pragma unroll
        for (int mk = 16; mk <= 32; mk <<= 1) {
            u64 o1 = __shfl_xor(a1, mk);
            u64 o2 = __shfl_xor(a2, mk);
            u64 n1 = a1 < o1 ? a1 : o1;
            u64 hi = a1 < o1 ? o1 : a1;
            u64 m2 = a2 < o2 ? a2 : o2;
            a1 = n1;
            a2 = hi < m2 ? hi : m2;
        }
        t1[j] = a1; t2[j] = a2;
    }

    // cross-wave (wn) merge via LDS, then write cand[row][ch][2]
    __syncthreads();
    u64* mbuf = (u64*)lds;                   // 2KB reuse
    if (wn == 1 && lg == 0) {
        #pragma unroll
        for (int j = 0; j < 4; ++j) {
            int s = ((wm * 4 + j) * 16 + lr) * 2;
            mbuf[s] = t1[j]; mbuf[s + 1] = t2[j];
        }
    }
    __syncthreads();
    if (wn == 0 && lg == 0) {
        #pragma unroll
        for (int j = 0; j < 4; ++j) {
            int s = ((wm * 4 + j) * 16 + lr) * 2;
            u64 b1 = mbuf[s], b2 = mbuf[s + 1];
            u64 n1 = t1[j] < b1 ? t1[j] : b1;
            u64 hi = t1[j] < b1 ? b1 : t1[j];
            u64 m2 = t2[j] < b2 ? t2[j] : b2;
            u64 n2 = hi < m2 ? hi : m2;
            int row = r0 + wm * 64 + j * 16 + lr;
            cand[((size_t)row * NCHUNK + ch) * 2]     = n1;
            cand[((size_t)row * NCHUNK + ch) * 2 + 1] = n2;
        }
    }
}

// ---------------- exact fp32 rescore of 16 candidates + outputs ----------------
__global__ __launch_bounds__(256) void rescore_kernel(const float* __restrict__ z,
                                                      const float* __restrict__ emb,
                                                      const float* __restrict__ enorm,
                                                      const u64* __restrict__ cand,
                                                      float* __restrict__ out,
                                                      float* __restrict__ partials) {
    int row  = blockIdx.x * 4 + (threadIdx.x >> 6);
    int lane = threadIdx.x & 63;
    float4 zv = reinterpret_cast<const float4*>(z)[(size_t)row * 64 + lane];

    u64 best = ~0ULL;
    for (int s = 0; s < 2 * NCHUNK; ++s) {
        u32 c = ((u32)cand[(size_t)row * (2 * NCHUNK) + s]) & (K_CODES - 1);
        float4 ev = reinterpret_cast<const float4*>(emb)[(size_t)c * 64 + lane];
        float p = zv.x * ev.x + zv.y * ev.y + zv.z * ev.z + zv.w * ev.w;
        #pragma unroll
        for (int mk = 1; mk < 64; mk <<= 1) p += __shfl_xor(p, mk);
        float dist = fmaf(-2.f, p, enorm[c]);
        u64 key = ((u64)f2ord(dist) << 32) | c;
        best = key < best ? key : best;
    }
    u32 idx = ((u32)best) & (K_CODES - 1);
    if (lane == 0) out[IDX_OFF + row] = (float)idx;

    float4 ev = reinterpret_cast<const float4*>(emb)[(size_t)idx * 64 + lane];
    float tx = ev.x - zv.x, ty = ev.y - zv.y, tz = ev.z - zv.z, tw = ev.w - zv.w;
    float4 o;
    o.x = zv.x + tx; o.y = zv.y + ty; o.z = zv.z + tz; o.w = zv.w + tw;  // straight-through
    reinterpret_cast<float4*>(out)[(size_t)row * 64 + lane] = o;

    float s = tx * tx + ty * ty + tz * tz + tw * tw;
    #pragma unroll
    for (int off = 32; off >= 1; off >>= 1) s += __shfl_down(s, off);

    __shared__ float wsum[4];
    if (lane == 0) wsum[threadIdx.x >> 6] = s;
    __syncthreads();
    if (threadIdx.x == 0)
        partials[blockIdx.x] = (wsum[0] + wsum[1]) + (wsum[2] + wsum[3]);
}

__global__ __launch_bounds__(256) void loss_kernel(const float* __restrict__ partials,
                                                   float* __restrict__ out) {
    __shared__ float sm[256];
    float s = 0.0f;
    for (int i = threadIdx.x; i < 4096; i += 256) s += partials[i];
    sm[threadIdx.x] = s;
    __syncthreads();
    #pragma unroll
    for (int st = 128; st >= 1; st >>= 1) {
        if (threadIdx.x < st) sm[threadIdx.x] += sm[threadIdx.x + st];
        __syncthreads();
    }
    if (threadIdx.x == 0)
        out[LOSS_OFF] = sm[0] * (0.25f / (float)(N_ROWS * D_DIM));
}

extern "C" void kernel_launch(void* const* d_in, const int* in_sizes, int n_in,
                              void* d_out, int out_size, void* d_ws, size_t ws_size,
                              hipStream_t stream) {
    const float* z   = (const float*)d_in[0];
    const float* emb = (const float*)d_in[1];
    float* out = (float*)d_out;

    u64*   cand     = (u64*)d_ws;
    float* enorm    = (float*)((char*)d_ws + WS_ENORM_OFF);
    float* partials = (float*)((char*)d_ws + WS_PARTIAL_OFF);
    unsigned short* zh = (unsigned short*)((char*)d_ws + WS_ZH_OFF);
    unsigned short* eh = (unsigned short*)((char*)d_ws + WS_EH_OFF);

    zconv_kernel<<<4096, 256, 0, stream>>>(z, zh);
    econv_kernel<<<2048, 256, 0, stream>>>(emb, eh, enorm);
    argmin_kernel<<<1024, 256, 0, stream>>>(zh, eh, enorm, cand);
    rescore_kernel<<<N_ROWS / 4, 256, 0, stream>>>(z, emb, enorm, cand, out, partials);
    loss_kernel<<<1, 256, 0, stream>>>(partials, out);
}